// Round 13
// baseline (10.559 us; speedup 1.0000x reference)
//
#include <hip/hip_runtime.h>

#define PI_OVER_2 1.57079632679489661923f

// Pauli/Heisenberg evaluation v2 — shared DPs. Anchored to the round-12-VERIFIED
// semantics (masks R_j/M_j, <X^aZ^b> with <XZ> = -i*y, coefficient products):
//
//  out_i = <phi| prod_{q in S_i} (C_q Z^{R_q} - S_q X^{M_q}) |phi>, S_i = R_i.
//
// FORWARD DP (outputs 1..6, S={0..i}, one shared sweep):
//   state st = d_prev | zeta0<<1 | H<<2 | P<<3   (H = hypothesis for total
//   parity T = par(zeta_1..i); P = prefix parity par(zeta_1..q)).
//   init (q=0): factor qubit0 = g(mX=d_0, mZ=H), coef C_0 / -S_0.
//   step q: factor qubit q = g(d_prev^d, zeta0^H^P), coef C_q / -S_q; P ^= 1-d.
//   closure i (after step i): states with H==P; x factor qubit i+1 g(d_prev,
//   zeta0); x tail prod_{j>i+1} z_j when zeta0. [verified symbolically vs the
//   r12 backward DP on outputs 1 and 2, all factor positions and parities]
//
// BACKWARD DP (outputs 0 and 7 share one sweep): r12 dp_eval<0,7> init +
// transitions verbatim; after the q=6..1 sweep, the gamma=0 subset IS
// dp_eval<1,7>'s state (same init values, same transitions) -> o0 closure
// (QMIN=1 rules) read-only; then one more step (q=0) + o7 closure (QMIN=0).

__global__ __launch_bounds__(256) void qpauli2_kernel(
        const float* __restrict__ x, const float* __restrict__ w,
        float* __restrict__ out, int nsamples) {
    const int sample = blockIdx.x * blockDim.x + threadIdx.x;
    if (sample >= nsamples) return;

    // ---- Bloch vectors (layer 1) + layer-2 coefficients, once per sample ----
    const float4* xv = reinterpret_cast<const float4*>(x + (size_t)sample * 8);
    const float4 xa = xv[0], xb = xv[1];
    const float xs[8] = {xa.x, xa.y, xa.z, xa.w, xb.x, xb.y, xb.z, xb.w};

    float C[8], S[8], zb[8], xbv[8], yb[8];
#pragma unroll
    for (int q = 0; q < 8; ++q) {
        const float A1 = fmaf(xs[q], PI_OVER_2, w[2 * q]);
        const float W  = w[2 * q + 1];
        const float A2 = fmaf(xs[q], PI_OVER_2, w[16 + 2 * q]);
        float s1v, c1v, sw, cw;
        __sincosf(A1, &s1v, &c1v);
        __sincosf(W, &sw, &cw);
        __sincosf(A2, &S[q], &C[q]);
        zb[q] = c1v;
        xbv[q] = s1v * cw;
        yb[q] = s1v * sw;
    }
    float ZT[9];   // ZT[k] = prod_{j=k..7} zb[j]
    ZT[8] = 1.f;
#pragma unroll
    for (int k = 7; k >= 2; --k) ZT[k] = zb[k] * ZT[k + 1];

    float o[8];

    // ================= FORWARD DP: outputs 1..6 =================
    float fre[16], fim[16];
#pragma unroll
    for (int i2 = 0; i2 < 16; ++i2) { fre[i2] = 0.f; fim[i2] = 0.f; }
    // init q=0: d0=0 -> st{z0=1}: H=0: 1 ; H=1: z_0.  d0=1 -> st{z0=0}:
    // H=0: -S0*x0 ; H=1: (-S0*y0)*(-i) -> im = +S0*y0.
    fre[2] = C[0];
    fre[6] = C[0] * zb[0];
    fre[1] = -S[0] * xbv[0];
    fim[5] = S[0] * yb[0];

#define FSTEP(Q)                                                              \
    {                                                                         \
        const float Cz = C[Q] * zb[Q], Cx = C[Q] * xbv[Q], Cy = C[Q] * yb[Q]; \
        const float Sz = S[Q] * zb[Q], Sx = S[Q] * xbv[Q], Sy = S[Q] * yb[Q]; \
        float nre[16], nim[16];                                               \
        _Pragma("unroll")                                                     \
        for (int i2 = 0; i2 < 16; ++i2) { nre[i2] = 0.f; nim[i2] = 0.f; }     \
        _Pragma("unroll")                                                     \
        for (int st = 0; st < 16; ++st) {                                     \
            const int dp_ = st & 1, z0 = (st >> 1) & 1;                       \
            const int H = (st >> 2) & 1, P = (st >> 3) & 1;                   \
            _Pragma("unroll")                                                 \
            for (int d = 0; d < 2; ++d) {                                     \
                const int mx = dp_ ^ d;                                       \
                const int mz = z0 ^ H ^ P;                                    \
                const int ns = d | (z0 << 1) | (H << 2) | ((P ^ d ^ 1) << 3); \
                if (mx == 0 && mz == 0) {                                     \
                    const float F = d ? -S[Q] : C[Q];                         \
                    nre[ns] = fmaf(F, fre[st], nre[ns]);                      \
                    nim[ns] = fmaf(F, fim[st], nim[ns]);                      \
                } else if (mx == 0 && mz == 1) {                              \
                    const float F = d ? -Sz : Cz;                             \
                    nre[ns] = fmaf(F, fre[st], nre[ns]);                      \
                    nim[ns] = fmaf(F, fim[st], nim[ns]);                      \
                } else if (mx == 1 && mz == 0) {                              \
                    const float F = d ? -Sx : Cx;                             \
                    nre[ns] = fmaf(F, fre[st], nre[ns]);                      \
                    nim[ns] = fmaf(F, fim[st], nim[ns]);                      \
                } else {  /* (-i*y): re' += F*im, im' -= F*re */              \
                    const float F = d ? -Sy : Cy;                             \
                    nre[ns] = fmaf(F, fim[st], nre[ns]);                      \
                    nim[ns] = fmaf(-F, fre[st], nim[ns]);                     \
                }                                                             \
            }                                                                 \
        }                                                                     \
        _Pragma("unroll")                                                     \
        for (int i2 = 0; i2 < 16; ++i2) { fre[i2] = nre[i2]; fim[i2] = nim[i2]; } \
    }

#define FCLOSE(I)                                                             \
    {                                                                         \
        const float tz = ZT[(I) + 1];               /* zb[I+1]*ZT[I+2] */     \
        const float ty = yb[(I) + 1] * ZT[(I) + 2];                           \
        const float tx = xbv[(I) + 1];                                        \
        float acc = 0.f;                                                      \
        _Pragma("unroll")                                                     \
        for (int st = 0; st < 16; ++st) {                                     \
            const int dp_ = st & 1, z0 = (st >> 1) & 1;                       \
            const int H = (st >> 2) & 1, P = (st >> 3) & 1;                   \
            if (H == P) {                                                     \
                if (dp_ == 0 && z0 == 0)      acc += fre[st];                 \
                else if (dp_ == 0 && z0 == 1) acc = fmaf(fre[st], tz, acc);   \
                else if (dp_ == 1 && z0 == 0) acc = fmaf(fre[st], tx, acc);   \
                else                          acc = fmaf(fim[st], ty, acc);   \
            }                                                                 \
        }                                                                     \
        o[I] = acc;                                                           \
    }

    FSTEP(1) FCLOSE(1)
    FSTEP(2) FCLOSE(2)
    FSTEP(3) FCLOSE(3)
    FSTEP(4) FCLOSE(4)
    FSTEP(5) FCLOSE(5)
    FSTEP(6) FCLOSE(6)
#undef FSTEP
#undef FCLOSE

    // ================= BACKWARD DP: outputs 0 and 7 =================
    // state st = dl | s1<<1 | g<<2 | dt<<3  (r12 encoding, verbatim)
    float bre[16], bim[16];
#pragma unroll
    for (int i2 = 0; i2 < 16; ++i2) { bre[i2] = 0.f; bim[i2] = 0.f; }
    bre[2] = C[7]; bre[6] = C[7];          // dl=0: idx 2 (g=0), 6 (g=1)
    bre[9] = -S[7]; bre[13] = -S[7];       // dl=1, dt=1: idx 9, 13

#define BSTEP(Q, ISQ0)                                                        \
    {                                                                         \
        const float Cz = C[Q] * zb[(Q) + 1], Cx = C[Q] * xbv[(Q) + 1];        \
        const float Cy = C[Q] * yb[(Q) + 1];                                  \
        const float Sz = S[Q] * zb[(Q) + 1], Sx = S[Q] * xbv[(Q) + 1];        \
        const float Sy = S[Q] * yb[(Q) + 1];                                  \
        float nre[16], nim[16];                                               \
        _Pragma("unroll")                                                     \
        for (int i2 = 0; i2 < 16; ++i2) { nre[i2] = 0.f; nim[i2] = 0.f; }     \
        _Pragma("unroll")                                                     \
        for (int st = 0; st < 16; ++st) {                                     \
            const int dp_ = st & 1, s1 = (st >> 1) & 1;                       \
            const int g = (st >> 2) & 1, dt = (st >> 3) & 1;                  \
            _Pragma("unroll")                                                 \
            for (int dl = 0; dl < 2; ++dl) {                                  \
                const int mx = dl ^ dp_ ^ ((ISQ0) ? dt : 0);                  \
                const int mz = g ^ s1;                                        \
                const int ns = dl | ((s1 ^ 1 ^ dl) << 1) | (g << 2) | (dt << 3); \
                if (mx == 0 && mz == 0) {                                     \
                    const float F = dl ? -S[Q] : C[Q];                        \
                    nre[ns] = fmaf(F, bre[st], nre[ns]);                      \
                    nim[ns] = fmaf(F, bim[st], nim[ns]);                      \
                } else if (mx == 0 && mz == 1) {                              \
                    const float F = dl ? -Sz : Cz;                            \
                    nre[ns] = fmaf(F, bre[st], nre[ns]);                      \
                    nim[ns] = fmaf(F, bim[st], nim[ns]);                      \
                } else if (mx == 1 && mz == 0) {                              \
                    const float F = dl ? -Sx : Cx;                            \
                    nre[ns] = fmaf(F, bre[st], nre[ns]);                      \
                    nim[ns] = fmaf(F, bim[st], nim[ns]);                      \
                } else {                                                      \
                    const float F = dl ? -Sy : Cy;                            \
                    nre[ns] = fmaf(F, bim[st], nre[ns]);                      \
                    nim[ns] = fmaf(-F, bre[st], nim[ns]);                     \
                }                                                             \
            }                                                                 \
        }                                                                     \
        _Pragma("unroll")                                                     \
        for (int i2 = 0; i2 < 16; ++i2) { bre[i2] = nre[i2]; bim[i2] = nim[i2]; } \
    }

    BSTEP(6, 0)
    BSTEP(5, 0)
    BSTEP(4, 0)
    BSTEP(3, 0)
    BSTEP(2, 0)
    BSTEP(1, 0)

#define APPLYG(MX, MZ, J)                                                     \
    if ((MX) == 0 && (MZ) == 1) { r *= zb[J]; i *= zb[J]; }                   \
    else if ((MX) == 1 && (MZ) == 0) { r *= xbv[J]; i *= xbv[J]; }            \
    else if ((MX) == 1 && (MZ) == 1) {                                        \
        const float t = r; r = i * yb[J]; i = -t * yb[J]; }

    // ---- o0 closure (gamma=0 subset == dp_eval<1,7> state; read-only) ----
    {
        float acc = 0.f;
#pragma unroll
        for (int st = 0; st < 16; ++st) {
            const int dp_ = st & 1, sf = (st >> 1) & 1;
            const int g = (st >> 2) & 1, dt = (st >> 3) & 1;
            if (g) continue;
            float r = bre[st], i = bim[st];
            APPLYG(dt, sf, 0)
            APPLYG(dp_ ^ dt, sf, 1)
            acc += r;
        }
        o[0] = acc;
    }

    // ---- final step q=0 (wrap in mx) + o7 closure ----
    BSTEP(0, 1)
    {
        float acc = 0.f;
#pragma unroll
        for (int st = 0; st < 16; ++st) {
            const int dp_ = st & 1, sf = (st >> 1) & 1;
            const int g = (st >> 2) & 1, dt = (st >> 3) & 1;
            if (g != (1 ^ dp_)) continue;   // gamma = zeta_0 = 1 - d0
            float r = bre[st], i = bim[st];
            APPLYG(dp_ ^ dt, sf ^ g, 0)
            acc += r;
        }
        o[7] = acc;
    }
#undef APPLYG
#undef BSTEP

    // ---- coalesced 32B store ----
    float4* ov = reinterpret_cast<float4*>(out + (size_t)sample * 8);
    ov[0] = make_float4(o[0], o[1], o[2], o[3]);
    ov[1] = make_float4(o[4], o[5], o[6], o[7]);
}

extern "C" void kernel_launch(void* const* d_in, const int* in_sizes, int n_in,
                              void* d_out, int out_size, void* d_ws, size_t ws_size,
                              hipStream_t stream) {
    const float* x = (const float*)d_in[0];
    const float* w = (const float*)d_in[1];
    float* outp = (float*)d_out;
    const int nsamples = in_sizes[0] / 8;
    const int block = 256;
    const int grid = (nsamples + block - 1) / block;
    qpauli2_kernel<<<grid, block, 0, stream>>>(x, w, outp, nsamples);
}

// Round 14
// 9.912 us; speedup vs baseline: 1.0653x; 1.0653x over previous
//
#include <hip/hip_runtime.h>

#define PI_OVER_2 1.57079632679489661923f

// Pauli/Heisenberg evaluation v3 — r13's VERIFIED shared DPs (forward prefix DP
// for outputs 1..6; backward DP for outputs 0 & 7), split across two
// wave-uniform lanes per sample (r12's mapping) for 2 waves/SIMD occupancy.
// DP semantics, masks, and closures are byte-identical to round 13 (passed at
// the 0.0039 reference floor). Only parallelization changed.

__global__ __launch_bounds__(256) void qpauli3_kernel(
        const float* __restrict__ x, const float* __restrict__ w,
        float* __restrict__ out, int nsamples) {
    const int gid = blockIdx.x * blockDim.x + threadIdx.x;
    const int wave = gid >> 6, lane = gid & 63;
    const int which = wave & 1;                 // wave-uniform: no divergence
    const int sample = (wave >> 1) * 64 + lane;
    if (sample >= nsamples) return;

    // ---- Bloch vectors (layer 1) + layer-2 coefficients ----
    const float4* xv = reinterpret_cast<const float4*>(x + (size_t)sample * 8);
    const float4 xa = xv[0], xb = xv[1];
    const float xs[8] = {xa.x, xa.y, xa.z, xa.w, xb.x, xb.y, xb.z, xb.w};

    float C[8], S[8], zb[8], xbv[8], yb[8];
#pragma unroll
    for (int q = 0; q < 8; ++q) {
        const float A1 = fmaf(xs[q], PI_OVER_2, w[2 * q]);
        const float W  = w[2 * q + 1];
        const float A2 = fmaf(xs[q], PI_OVER_2, w[16 + 2 * q]);
        float s1v, c1v, sw, cw;
        __sincosf(A1, &s1v, &c1v);
        __sincosf(W, &sw, &cw);
        __sincosf(A2, &S[q], &C[q]);
        zb[q] = c1v;
        xbv[q] = s1v * cw;
        yb[q] = s1v * sw;
    }

    float* o = out + (size_t)sample * 8;

    float Are[16], Aim[16], Bre[16], Bim[16];
#pragma unroll
    for (int i2 = 0; i2 < 16; ++i2) { Are[i2] = 0.f; Aim[i2] = 0.f; }

    if (which == 0) {
        // ================= FORWARD DP: outputs 1..6 =================
        float ZT[9];   // ZT[k] = prod_{j=k..7} zb[j]
        ZT[8] = 1.f;
#pragma unroll
        for (int k = 7; k >= 2; --k) ZT[k] = zb[k] * ZT[k + 1];

        // init q=0 (r13 verbatim)
        Are[2] = C[0];
        Are[6] = C[0] * zb[0];
        Are[1] = -S[0] * xbv[0];
        Aim[5] = S[0] * yb[0];

#define FSTEP(Q, IRE, IIM, ORE, OIM)                                          \
    {                                                                         \
        const float Cz = C[Q] * zb[Q], Cx = C[Q] * xbv[Q], Cy = C[Q] * yb[Q]; \
        const float Sz = S[Q] * zb[Q], Sx = S[Q] * xbv[Q], Sy = S[Q] * yb[Q]; \
        _Pragma("unroll")                                                     \
        for (int i2 = 0; i2 < 16; ++i2) { ORE[i2] = 0.f; OIM[i2] = 0.f; }     \
        _Pragma("unroll")                                                     \
        for (int st = 0; st < 16; ++st) {                                     \
            const int dp_ = st & 1, z0 = (st >> 1) & 1;                       \
            const int H = (st >> 2) & 1, P = (st >> 3) & 1;                   \
            _Pragma("unroll")                                                 \
            for (int d = 0; d < 2; ++d) {                                     \
                const int mx = dp_ ^ d;                                       \
                const int mz = z0 ^ H ^ P;                                    \
                const int ns = d | (z0 << 1) | (H << 2) | ((P ^ d ^ 1) << 3); \
                if (mx == 0 && mz == 0) {                                     \
                    const float F = d ? -S[Q] : C[Q];                         \
                    ORE[ns] = fmaf(F, IRE[st], ORE[ns]);                      \
                    OIM[ns] = fmaf(F, IIM[st], OIM[ns]);                      \
                } else if (mx == 0 && mz == 1) {                              \
                    const float F = d ? -Sz : Cz;                             \
                    ORE[ns] = fmaf(F, IRE[st], ORE[ns]);                      \
                    OIM[ns] = fmaf(F, IIM[st], OIM[ns]);                      \
                } else if (mx == 1 && mz == 0) {                              \
                    const float F = d ? -Sx : Cx;                             \
                    ORE[ns] = fmaf(F, IRE[st], ORE[ns]);                      \
                    OIM[ns] = fmaf(F, IIM[st], OIM[ns]);                      \
                } else {  /* (-i*y) */                                        \
                    const float F = d ? -Sy : Cy;                             \
                    ORE[ns] = fmaf(F, IIM[st], ORE[ns]);                      \
                    OIM[ns] = fmaf(-F, IRE[st], OIM[ns]);                     \
                }                                                             \
            }                                                                 \
        }                                                                     \
    }

#define FCLOSE(I, RRE, RIM)                                                   \
    {                                                                         \
        const float tz = ZT[(I) + 1];                                         \
        const float ty = yb[(I) + 1] * ZT[(I) + 2];                           \
        const float tx = xbv[(I) + 1];                                        \
        float acc = 0.f;                                                      \
        _Pragma("unroll")                                                     \
        for (int st = 0; st < 16; ++st) {                                     \
            const int dp_ = st & 1, z0 = (st >> 1) & 1;                       \
            const int H = (st >> 2) & 1, P = (st >> 3) & 1;                   \
            if (H == P) {                                                     \
                if (dp_ == 0 && z0 == 0)      acc += RRE[st];                 \
                else if (dp_ == 0 && z0 == 1) acc = fmaf(RRE[st], tz, acc);   \
                else if (dp_ == 1 && z0 == 0) acc = fmaf(RRE[st], tx, acc);   \
                else                          acc = fmaf(RIM[st], ty, acc);   \
            }                                                                 \
        }                                                                     \
        o[I] = acc;                                                           \
    }

        FSTEP(1, Are, Aim, Bre, Bim) FCLOSE(1, Bre, Bim)
        FSTEP(2, Bre, Bim, Are, Aim) FCLOSE(2, Are, Aim)
        FSTEP(3, Are, Aim, Bre, Bim) FCLOSE(3, Bre, Bim)
        FSTEP(4, Bre, Bim, Are, Aim) FCLOSE(4, Are, Aim)
        FSTEP(5, Are, Aim, Bre, Bim) FCLOSE(5, Bre, Bim)
        FSTEP(6, Bre, Bim, Are, Aim) FCLOSE(6, Are, Aim)
#undef FSTEP
#undef FCLOSE
    } else {
        // ================= BACKWARD DP: outputs 0 and 7 =================
        Are[2] = C[7]; Are[6] = C[7];
        Are[9] = -S[7]; Are[13] = -S[7];

#define BSTEP(Q, ISQ0, IRE, IIM, ORE, OIM)                                    \
    {                                                                         \
        const float Cz = C[Q] * zb[(Q) + 1], Cx = C[Q] * xbv[(Q) + 1];        \
        const float Cy = C[Q] * yb[(Q) + 1];                                  \
        const float Sz = S[Q] * zb[(Q) + 1], Sx = S[Q] * xbv[(Q) + 1];        \
        const float Sy = S[Q] * yb[(Q) + 1];                                  \
        _Pragma("unroll")                                                     \
        for (int i2 = 0; i2 < 16; ++i2) { ORE[i2] = 0.f; OIM[i2] = 0.f; }     \
        _Pragma("unroll")                                                     \
        for (int st = 0; st < 16; ++st) {                                     \
            const int dp_ = st & 1, s1 = (st >> 1) & 1;                       \
            const int g = (st >> 2) & 1, dt = (st >> 3) & 1;                  \
            _Pragma("unroll")                                                 \
            for (int dl = 0; dl < 2; ++dl) {                                  \
                const int mx = dl ^ dp_ ^ ((ISQ0) ? dt : 0);                  \
                const int mz = g ^ s1;                                        \
                const int ns = dl | ((s1 ^ 1 ^ dl) << 1) | (g << 2) | (dt << 3); \
                if (mx == 0 && mz == 0) {                                     \
                    const float F = dl ? -S[Q] : C[Q];                        \
                    ORE[ns] = fmaf(F, IRE[st], ORE[ns]);                      \
                    OIM[ns] = fmaf(F, IIM[st], OIM[ns]);                      \
                } else if (mx == 0 && mz == 1) {                              \
                    const float F = dl ? -Sz : Cz;                            \
                    ORE[ns] = fmaf(F, IRE[st], ORE[ns]);                      \
                    OIM[ns] = fmaf(F, IIM[st], OIM[ns]);                      \
                } else if (mx == 1 && mz == 0) {                              \
                    const float F = dl ? -Sx : Cx;                            \
                    ORE[ns] = fmaf(F, IRE[st], ORE[ns]);                      \
                    OIM[ns] = fmaf(F, IIM[st], OIM[ns]);                      \
                } else {                                                      \
                    const float F = dl ? -Sy : Cy;                            \
                    ORE[ns] = fmaf(F, IIM[st], ORE[ns]);                      \
                    OIM[ns] = fmaf(-F, IRE[st], OIM[ns]);                     \
                }                                                             \
            }                                                                 \
        }                                                                     \
    }

        BSTEP(6, 0, Are, Aim, Bre, Bim)
        BSTEP(5, 0, Bre, Bim, Are, Aim)
        BSTEP(4, 0, Are, Aim, Bre, Bim)
        BSTEP(3, 0, Bre, Bim, Are, Aim)
        BSTEP(2, 0, Are, Aim, Bre, Bim)
        BSTEP(1, 0, Bre, Bim, Are, Aim)

#define APPLYG(MX, MZ, J)                                                     \
    if ((MX) == 0 && (MZ) == 1) { r *= zb[J]; i *= zb[J]; }                   \
    else if ((MX) == 1 && (MZ) == 0) { r *= xbv[J]; i *= xbv[J]; }            \
    else if ((MX) == 1 && (MZ) == 1) {                                        \
        const float t = r; r = i * yb[J]; i = -t * yb[J]; }

        // ---- o0 closure (gamma=0 subset; reads Are/Aim) ----
        {
            float acc = 0.f;
#pragma unroll
            for (int st = 0; st < 16; ++st) {
                const int dp_ = st & 1, sf = (st >> 1) & 1;
                const int g = (st >> 2) & 1, dt = (st >> 3) & 1;
                if (g) continue;
                float r = Are[st], i = Aim[st];
                APPLYG(dt, sf, 0)
                APPLYG(dp_ ^ dt, sf, 1)
                acc += r;
            }
            o[0] = acc;
        }

        // ---- final step q=0 (wrap in mx) + o7 closure ----
        BSTEP(0, 1, Are, Aim, Bre, Bim)
        {
            float acc = 0.f;
#pragma unroll
            for (int st = 0; st < 16; ++st) {
                const int dp_ = st & 1, sf = (st >> 1) & 1;
                const int g = (st >> 2) & 1, dt = (st >> 3) & 1;
                if (g != (1 ^ dp_)) continue;   // gamma = zeta_0 = 1 - d0
                float r = Bre[st], i = Bim[st];
                APPLYG(dp_ ^ dt, sf ^ g, 0)
                acc += r;
            }
            o[7] = acc;
        }
#undef APPLYG
#undef BSTEP
    }
}

extern "C" void kernel_launch(void* const* d_in, const int* in_sizes, int n_in,
                              void* d_out, int out_size, void* d_ws, size_t ws_size,
                              hipStream_t stream) {
    const float* x = (const float*)d_in[0];
    const float* w = (const float*)d_in[1];
    float* outp = (float*)d_out;
    const int nsamples = in_sizes[0] / 8;
    const int nthreads = nsamples * 2;
    const int block = 256;
    const int grid = (nthreads + block - 1) / block;
    qpauli3_kernel<<<grid, block, 0, stream>>>(x, w, outp, nsamples);
}